// Round 3
// baseline (9102.324 us; speedup 1.0000x reference)
//
#include <hip/hip_runtime.h>
#include <cstddef>
#include <cstdint>

#define LSEQ 4096
#define NB 8
#define DM 256
#define DI 512

__device__ __forceinline__ float softplus_f(float x) {
  return (x > 20.f) ? x : log1pf(__expf(x));
}

// ---------------- gather: build x[b,l,c] from stack_feats via spiral order ----------------
__global__ void gather_kernel(const float* __restrict__ sf, const int* __restrict__ co,
                              float* __restrict__ x) {
  int bl = blockIdx.x;           // b*4096 + l
  int l = bl & (LSEQ - 1);
  int b = bl >> 12;
  int c = threadIdx.x;           // 0..255
  int hw = co[l];
  int bb = b + ((c >= 128) ? NB : 0);
  int cc = c & 127;
  float v = sf[(((size_t)bb * 128) + cc) * 4096 + hw];
  x[(size_t)bl * DM + c] = v;
}

// ---------------- layernorm over d_model=256, one 64-lane wave per row ----------------
__global__ void ln_kernel(const float* __restrict__ x, const float* __restrict__ w,
                          const float* __restrict__ bwt, float* __restrict__ out) {
  int row = blockIdx.x;
  int lane = threadIdx.x;        // 0..63
  float4 v = ((const float4*)(x + (size_t)row * DM))[lane];
  float s = v.x + v.y + v.z + v.w;
  float s2 = v.x * v.x + v.y * v.y + v.z * v.z + v.w * v.w;
#pragma unroll
  for (int off = 32; off > 0; off >>= 1) {
    s += __shfl_xor(s, off);
    s2 += __shfl_xor(s2, off);
  }
  float mu = s * (1.0f / DM);
  float var = s2 * (1.0f / DM) - mu * mu;
  float rstd = rsqrtf(var + 1e-5f);
  float4 wv = ((const float4*)w)[lane];
  float4 bv = ((const float4*)bwt)[lane];
  float4 o;
  o.x = (v.x - mu) * rstd * wv.x + bv.x;
  o.y = (v.y - mu) * rstd * wv.y + bv.y;
  o.z = (v.z - mu) * rstd * wv.z + bv.z;
  o.w = (v.w - mu) * rstd * wv.w + bv.w;
  ((float4*)(out + (size_t)row * DM))[lane] = o;
}

// ---------------- generic fp32 GEMM: C[m,n] = dot(A[m,:K], W[n,:K]) (+epilogue) ----------
// EPI: 0 = plain store, 1 = softplus(dot + bias[n]), 2 = C[m,n] += dot (residual in-place)
// BM=BN=128, BK=16, 256 threads, 8x8 microtile.
template <int EPI>
__global__ __launch_bounds__(256) void gemm_kernel(
    const float* __restrict__ A, int lda,
    const float* __restrict__ W,                 // [N,K] row-major
    float* __restrict__ C, int ldc, int N, int K,
    const float* __restrict__ bias) {
  __shared__ __align__(16) float As[16][132];
  __shared__ __align__(16) float Bs[16][132];
  const int bm = blockIdx.x * 128;
  const int bn = blockIdx.y * 128;
  const int t = threadIdx.x;
  const int tx = t & 15;
  const int ty = t >> 4;
  const int lr = t >> 2;         // 0..63
  const int k4 = (t & 3) * 4;    // 0,4,8,12
  float acc[8][8];
#pragma unroll
  for (int i = 0; i < 8; ++i)
#pragma unroll
    for (int j = 0; j < 8; ++j) acc[i][j] = 0.f;

  for (int k0 = 0; k0 < K; k0 += 16) {
#pragma unroll
    for (int h = 0; h < 2; ++h) {
      int r = lr + h * 64;
      float4 av = *(const float4*)(A + (size_t)(bm + r) * lda + (k0 + k4));
      As[(k4 + 0) & 15][r] = av.x; As[(k4 + 1) & 15][r] = av.y;
      As[(k4 + 2) & 15][r] = av.z; As[(k4 + 3) & 15][r] = av.w;
      int n = bn + r;
      float4 wv = make_float4(0.f, 0.f, 0.f, 0.f);
      if (n < N) wv = *(const float4*)(W + (size_t)n * K + (k0 + k4));
      Bs[(k4 + 0) & 15][r] = wv.x; Bs[(k4 + 1) & 15][r] = wv.y;
      Bs[(k4 + 2) & 15][r] = wv.z; Bs[(k4 + 3) & 15][r] = wv.w;
    }
    __syncthreads();
#pragma unroll
    for (int k = 0; k < 16; ++k) {
      float a[8], bb[8];
      *(float4*)&a[0] = *(const float4*)&As[k][ty * 8];
      *(float4*)&a[4] = *(const float4*)&As[k][ty * 8 + 4];
      *(float4*)&bb[0] = *(const float4*)&Bs[k][tx * 8];
      *(float4*)&bb[4] = *(const float4*)&Bs[k][tx * 8 + 4];
#pragma unroll
      for (int i = 0; i < 8; ++i)
#pragma unroll
        for (int j = 0; j < 8; ++j) acc[i][j] = fmaf(a[i], bb[j], acc[i][j]);
    }
    __syncthreads();
  }

#pragma unroll
  for (int i = 0; i < 8; ++i) {
    int m = bm + ty * 8 + i;
    float* crow = C + (size_t)m * ldc;
#pragma unroll
    for (int j4 = 0; j4 < 2; ++j4) {
      int n0 = bn + tx * 8 + j4 * 4;
      if (n0 < N) {  // N is always a multiple of 4
        float4 o;
        const float* pa = &acc[i][j4 * 4];
        if (EPI == 0) {
          o = make_float4(pa[0], pa[1], pa[2], pa[3]);
        } else if (EPI == 1) {
          float4 bb4 = *(const float4*)(bias + n0);
          o.x = softplus_f(pa[0] + bb4.x);
          o.y = softplus_f(pa[1] + bb4.y);
          o.z = softplus_f(pa[2] + bb4.z);
          o.w = softplus_f(pa[3] + bb4.w);
        } else {
          float4 r0 = *(const float4*)(crow + n0);
          o = make_float4(r0.x + pa[0], r0.y + pa[1], r0.z + pa[2], r0.w + pa[3]);
        }
        *(float4*)(crow + n0) = o;
      }
    }
  }
}

// ---------------- causal depthwise conv K=4 + bias + silu ----------------
__global__ void conv_silu_kernel(const float* __restrict__ xz, const float* __restrict__ wc,
                                 const float* __restrict__ bc, float* __restrict__ u) {
  size_t idx = (size_t)blockIdx.x * 256 + threadIdx.x;   // (b*L + l)*512 + d
  int d = (int)(idx & (DI - 1));
  size_t bl = idx >> 9;
  int l = (int)(bl & (LSEQ - 1));
  const float* base = xz + bl * 1024 + d;                // u half of xz
  float4 wv = *(const float4*)(wc + d * 4);
  float acc = bc[d] + wv.w * base[0];
  if (l >= 1) acc = fmaf(wv.z, base[-1024], acc);
  if (l >= 2) acc = fmaf(wv.y, base[-2048], acc);
  if (l >= 3) acc = fmaf(wv.x, base[-3072], acc);
  float s = acc / (1.f + __expf(-acc));
  u[bl * DI + d] = s;
}

// ---------------- selective scan, fused +u*D and silu(z) gate, y in-place over u -------
// grid: 64 blocks = 8 b x 8 d-blocks; block: 256 threads = 4 waves x (16 d x 4 s-groups)
__global__ __launch_bounds__(256) void scan_kernel(
    const float* __restrict__ xz,        // dt in [:, :512], z in [:, 512:]
    float* __restrict__ u,               // in: conv-silu u; out: gated y
    const float* __restrict__ xdbl,     // [M,48]: cols 16..31 = B, 32..47 = C
    const float* __restrict__ A_log, const float* __restrict__ Dp) {
  int b = blockIdx.x >> 3;
  int dblk = blockIdx.x & 7;
  int lane = threadIdx.x & 63;
  int wave = threadIdx.x >> 6;
  int dl = lane >> 2;            // 0..15
  int sg = lane & 3;             // 0..3 -> states sg*4 .. sg*4+3
  int d = dblk * 64 + wave * 16 + dl;
  float4 al = *(const float4*)(A_log + d * 16 + sg * 4);
  float A0 = -__expf(al.x), A1 = -__expf(al.y), A2 = -__expf(al.z), A3 = -__expf(al.w);
  float Dd = Dp[d];
  float h0 = 0.f, h1 = 0.f, h2 = 0.f, h3 = 0.f;
  size_t mbase = (size_t)b * LSEQ;

  // prefetch t=0
  float dtv = xz[mbase * 1024 + d];
  float zv  = xz[mbase * 1024 + 512 + d];
  float uv  = u[mbase * DI + d];
  float4 Bv = *(const float4*)(xdbl + mbase * 48 + 16 + sg * 4);
  float4 Cv = *(const float4*)(xdbl + mbase * 48 + 32 + sg * 4);

  for (int t = 0; t < LSEQ; ++t) {
    float ndt = 0.f, nz = 0.f, nu = 0.f;
    float4 nB = make_float4(0.f, 0.f, 0.f, 0.f), nC = nB;
    if (t + 1 < LSEQ) {
      size_t m2 = mbase + t + 1;
      ndt = xz[m2 * 1024 + d];
      nz  = xz[m2 * 1024 + 512 + d];
      nu  = u[m2 * DI + d];
      nB  = *(const float4*)(xdbl + m2 * 48 + 16 + sg * 4);
      nC  = *(const float4*)(xdbl + m2 * 48 + 32 + sg * 4);
    }
    float dtu = dtv * uv;
    h0 = fmaf(__expf(dtv * A0), h0, dtu * Bv.x);
    h1 = fmaf(__expf(dtv * A1), h1, dtu * Bv.y);
    h2 = fmaf(__expf(dtv * A2), h2, dtu * Bv.z);
    h3 = fmaf(__expf(dtv * A3), h3, dtu * Bv.w);
    float y = h0 * Cv.x + h1 * Cv.y + h2 * Cv.z + h3 * Cv.w;
    y += __shfl_xor(y, 1);
    y += __shfl_xor(y, 2);
    if (sg == 0) {
      float yf = y + uv * Dd;
      float sz = zv / (1.f + __expf(-zv));
      u[(mbase + t) * DI + d] = yf * sz;
    }
    dtv = ndt; zv = nz; uv = nu; Bv = nB; Cv = nC;
  }
}

// ---------------- final LN + scatter back to raster order ----------------
__global__ void lnf_scatter_kernel(const float* __restrict__ x, const float* __restrict__ w,
                                   const float* __restrict__ bwt, const int* __restrict__ co,
                                   float* __restrict__ out) {
  int row = blockIdx.x;          // b*4096 + l
  int b = row >> 12;
  int l = row & (LSEQ - 1);
  int lane = threadIdx.x;
  float4 v = ((const float4*)(x + (size_t)row * DM))[lane];
  float s = v.x + v.y + v.z + v.w;
  float s2 = v.x * v.x + v.y * v.y + v.z * v.z + v.w * v.w;
#pragma unroll
  for (int off = 32; off > 0; off >>= 1) {
    s += __shfl_xor(s, off);
    s2 += __shfl_xor(s2, off);
  }
  float mu = s * (1.0f / DM);
  float var = s2 * (1.0f / DM) - mu * mu;
  float rstd = rsqrtf(var + 1e-5f);
  float4 wv = ((const float4*)w)[lane];
  float4 bv = ((const float4*)bwt)[lane];
  float4 o;
  o.x = (v.x - mu) * rstd * wv.x + bv.x;
  o.y = (v.y - mu) * rstd * wv.y + bv.y;
  o.z = (v.z - mu) * rstd * wv.z + bv.z;
  o.w = (v.w - mu) * rstd * wv.w + bv.w;
  int hw = co[l];
  int c0 = lane * 4;
  size_t obase = ((size_t)b * DM + c0) * 4096 + hw;
  out[obase + 0 * 4096] = o.x;
  out[obase + 1 * 4096] = o.y;
  out[obase + 2 * 4096] = o.z;
  out[obase + 3 * 4096] = o.w;
}

extern "C" void kernel_launch(void* const* d_in, const int* in_sizes, int n_in,
                              void* d_out, int out_size, void* d_ws, size_t ws_size,
                              hipStream_t stream) {
  (void)in_sizes; (void)n_in; (void)out_size; (void)ws_size;
  const float* sf   = (const float*)d_in[0];
  const float* lnw  = (const float*)d_in[1];
  const float* lnb  = (const float*)d_in[2];
  const float* inw  = (const float*)d_in[3];
  const float* cw   = (const float*)d_in[4];
  const float* cb   = (const float*)d_in[5];
  const float* xpw  = (const float*)d_in[6];
  const float* dtw  = (const float*)d_in[7];
  const float* dtb  = (const float*)d_in[8];
  const float* alog = (const float*)d_in[9];
  const float* dp   = (const float*)d_in[10];
  const float* ow   = (const float*)d_in[11];
  const float* lnfw = (const float*)d_in[12];
  const float* lnfb = (const float*)d_in[13];
  const int*   co   = (const int*)d_in[14];
  float* out = (float*)d_out;

  float* ws = (float*)d_ws;
  // workspace layout (floats): x 8.39M | x_ln/x_dbl 8.39M | xz 33.55M | u 16.78M  = 256 MiB
  float* x    = ws;
  float* xln  = ws + 8388608;
  float* xdbl = xln;                    // aliases x_ln (x_ln dead once x_proj runs)
  float* xz   = ws + 16777216;
  float* u    = ws + 50331648;

  const int ROWS = NB * LSEQ;           // 32768

  gather_kernel<<<ROWS, 256, 0, stream>>>(sf, co, x);

  for (int i = 0; i < 4; ++i) {
    ln_kernel<<<ROWS, 64, 0, stream>>>(x, lnw + i * DM, lnb + i * DM, xln);
    // in_proj: [32768,256] x [1024,256]^T -> xz [32768,1024]
    gemm_kernel<0><<<dim3(ROWS / 128, 8), 256, 0, stream>>>(
        xln, DM, inw + (size_t)i * 1024 * DM, xz, 1024, 1024, DM, nullptr);
    // causal depthwise conv + silu -> u
    conv_silu_kernel<<<(ROWS * DI) / 256, 256, 0, stream>>>(
        xz, cw + i * DI * 4, cb + i * DI, u);
    // x_proj: [32768,512] x [48,512]^T -> x_dbl [32768,48]
    gemm_kernel<0><<<dim3(ROWS / 128, 1), 256, 0, stream>>>(
        u, DI, xpw + (size_t)i * 48 * DI, xdbl, 48, 48, DI, nullptr);
    // dt_proj: [32768,16] x [512,16]^T + b, softplus -> dt stored in xz[:, :512]
    gemm_kernel<1><<<dim3(ROWS / 128, 4), 256, 0, stream>>>(
        xdbl, 48, dtw + (size_t)i * DI * 16, xz, 1024, DI, 16, dtb + i * DI);
    // selective scan + gate: y (in-place over u)
    scan_kernel<<<64, 256, 0, stream>>>(xz, u, xdbl, alog + i * DI * 16, dp + i * DI);
    // out_proj + residual: x += y x [256,512]^T
    gemm_kernel<2><<<dim3(ROWS / 128, 2), 256, 0, stream>>>(
        u, DI, ow + (size_t)i * DM * DI, x, DM, DM, DI, nullptr);
  }

  lnf_scatter_kernel<<<ROWS, 64, 0, stream>>>(x, lnfw, lnfb, co, out);
}

// Round 5
// 2393.500 us; speedup vs baseline: 3.8029x; 3.8029x over previous
//
#include <hip/hip_runtime.h>
#include <cstddef>
#include <cstdint>

#define LSEQ 4096
#define NB 8
#define DM 256
#define DI 512
#define CHUNK 128
#define NCHUNK 32

typedef short bf16x8 __attribute__((ext_vector_type(8)));
typedef float f32x4 __attribute__((ext_vector_type(4)));

__device__ __forceinline__ float softplus_f(float x) {
  return (x > 20.f) ? x : log1pf(__expf(x));
}

__device__ __forceinline__ short f2bf(float f) {
  union { float f; uint32_t u; } v; v.f = f;
  uint32_t u = v.u;
  uint32_t r = (u + 0x7FFFu + ((u >> 16) & 1u)) >> 16;   // round-nearest-even
  return (short)r;
}

__device__ __forceinline__ void pack8(const float4& a, const float4& b, short* dst) {
  bf16x8 v;
  v[0] = f2bf(a.x); v[1] = f2bf(a.y); v[2] = f2bf(a.z); v[3] = f2bf(a.w);
  v[4] = f2bf(b.x); v[5] = f2bf(b.y); v[6] = f2bf(b.z); v[7] = f2bf(b.w);
  *(bf16x8*)dst = v;
}

// ---------------- gather: build x[b,l,c] from stack_feats via spiral order ----------------
__global__ void gather_kernel(const float* __restrict__ sf, const int* __restrict__ co,
                              float* __restrict__ x) {
  int bl = blockIdx.x;           // b*4096 + l
  int l = bl & (LSEQ - 1);
  int b = bl >> 12;
  int c = threadIdx.x;           // 0..255
  int hw = co[l];
  int bb = b + ((c >= 128) ? NB : 0);
  int cc = c & 127;
  float v = sf[(((size_t)bb * 128) + cc) * 4096 + hw];
  x[(size_t)bl * DM + c] = v;
}

// ---------------- layernorm over d_model=256, one 64-lane wave per row ----------------
__global__ void ln_kernel(const float* __restrict__ x, const float* __restrict__ w,
                          const float* __restrict__ bwt, float* __restrict__ out) {
  int row = blockIdx.x;
  int lane = threadIdx.x;        // 0..63
  float4 v = ((const float4*)(x + (size_t)row * DM))[lane];
  float s = v.x + v.y + v.z + v.w;
  float s2 = v.x * v.x + v.y * v.y + v.z * v.z + v.w * v.w;
#pragma unroll
  for (int off = 32; off > 0; off >>= 1) {
    s += __shfl_xor(s, off);
    s2 += __shfl_xor(s2, off);
  }
  float mu = s * (1.0f / DM);
  float var = s2 * (1.0f / DM) - mu * mu;
  float rstd = rsqrtf(var + 1e-5f);
  float4 wv = ((const float4*)w)[lane];
  float4 bv = ((const float4*)bwt)[lane];
  float4 o;
  o.x = (v.x - mu) * rstd * wv.x + bv.x;
  o.y = (v.y - mu) * rstd * wv.y + bv.y;
  o.z = (v.z - mu) * rstd * wv.z + bv.z;
  o.w = (v.w - mu) * rstd * wv.w + bv.w;
  ((float4*)(out + (size_t)row * DM))[lane] = o;
}

// ---------------- bf16 MFMA GEMM: C[m,n] = dot(A[m,:K], W[n,:K]) ----------------
// EPI: 0 = plain store, 2 = C += dot (residual). Tiles: BM=BN=64, BK=32.
// 256 threads = 4 waves, each wave owns a 32x32 quadrant = 2x2 mfma_f32_16x16x32_bf16.
// A,W are fp32 in memory; converted to bf16 (RNE) while staging into LDS.
// Requires: M%64==0, N%64==0, K%32==0.
template <int EPI>
__global__ __launch_bounds__(256) void mfma_gemm(
    const float* __restrict__ A, int lda,
    const float* __restrict__ W,                 // [N,K] row-major
    float* __restrict__ C, int ldc, int K) {
  __shared__ __align__(16) short As[64][40];     // pad to 40 bf16 (80 B rows)
  __shared__ __align__(16) short Bs[64][40];
  const int bm = blockIdx.x * 64;
  const int bn = blockIdx.y * 64;
  const int t = threadIdx.x;
  const int lane = t & 63;
  const int wave = t >> 6;
  const int srow = t >> 2;        // staging row 0..63
  const int skoff = (t & 3) * 8;  // staging k-offset 0,8,16,24
  const int wm = (wave >> 1) * 32;
  const int wn = (wave & 1) * 32;
  const int fr = lane & 15;       // frag row (A) / col (B) / col (D)
  const int fk = (lane >> 4) * 8; // frag k-offset
  const int r4 = (lane >> 4) * 4; // D row base

  f32x4 acc[2][2];
#pragma unroll
  for (int i = 0; i < 2; ++i)
#pragma unroll
    for (int j = 0; j < 2; ++j) acc[i][j] = (f32x4){0.f, 0.f, 0.f, 0.f};

  const float* pa = A + (size_t)(bm + srow) * lda + skoff;
  const float* pb = W + (size_t)(bn + srow) * K + skoff;

  for (int k0 = 0; k0 < K; k0 += 32) {
    float4 a0 = *(const float4*)(pa + k0);
    float4 a1 = *(const float4*)(pa + k0 + 4);
    float4 b0 = *(const float4*)(pb + k0);
    float4 b1 = *(const float4*)(pb + k0 + 4);
    pack8(a0, a1, &As[srow][skoff]);
    pack8(b0, b1, &Bs[srow][skoff]);
    __syncthreads();
    bf16x8 af[2], bfv[2];
    af[0]  = *(const bf16x8*)&As[wm + fr][fk];
    af[1]  = *(const bf16x8*)&As[wm + 16 + fr][fk];
    bfv[0] = *(const bf16x8*)&Bs[wn + fr][fk];
    bfv[1] = *(const bf16x8*)&Bs[wn + 16 + fr][fk];
#pragma unroll
    for (int mi = 0; mi < 2; ++mi)
#pragma unroll
      for (int ni = 0; ni < 2; ++ni)
        acc[mi][ni] = __builtin_amdgcn_mfma_f32_16x16x32_bf16(
            af[mi], bfv[ni], acc[mi][ni], 0, 0, 0);
    __syncthreads();
  }

#pragma unroll
  for (int mi = 0; mi < 2; ++mi)
#pragma unroll
    for (int ni = 0; ni < 2; ++ni) {
      int col = bn + wn + ni * 16 + fr;
#pragma unroll
      for (int r = 0; r < 4; ++r) {
        int row = bm + wm + mi * 16 + r4 + r;
        float* p = C + (size_t)row * ldc + col;
        if (EPI == 2) *p += acc[mi][ni][r];
        else          *p  = acc[mi][ni][r];
      }
    }
}

// ---------------- generic fp32 GEMM (small shapes): C = A·W^T (+epilogue) ----------
// EPI: 0 = plain store, 1 = softplus(dot + bias[n])
template <int EPI>
__global__ __launch_bounds__(256) void gemm_kernel(
    const float* __restrict__ A, int lda,
    const float* __restrict__ W,                 // [N,K] row-major
    float* __restrict__ C, int ldc, int N, int K,
    const float* __restrict__ bias) {
  __shared__ __align__(16) float As[16][132];
  __shared__ __align__(16) float Bs[16][132];
  const int bm = blockIdx.x * 128;
  const int bn = blockIdx.y * 128;
  const int t = threadIdx.x;
  const int tx = t & 15;
  const int ty = t >> 4;
  const int lr = t >> 2;         // 0..63
  const int k4 = (t & 3) * 4;    // 0,4,8,12
  float acc[8][8];
#pragma unroll
  for (int i = 0; i < 8; ++i)
#pragma unroll
    for (int j = 0; j < 8; ++j) acc[i][j] = 0.f;

  for (int k0 = 0; k0 < K; k0 += 16) {
#pragma unroll
    for (int h = 0; h < 2; ++h) {
      int r = lr + h * 64;
      float4 av = *(const float4*)(A + (size_t)(bm + r) * lda + (k0 + k4));
      As[(k4 + 0) & 15][r] = av.x; As[(k4 + 1) & 15][r] = av.y;
      As[(k4 + 2) & 15][r] = av.z; As[(k4 + 3) & 15][r] = av.w;
      int n = bn + r;
      float4 wv = make_float4(0.f, 0.f, 0.f, 0.f);
      if (n < N) wv = *(const float4*)(W + (size_t)n * K + (k0 + k4));
      Bs[(k4 + 0) & 15][r] = wv.x; Bs[(k4 + 1) & 15][r] = wv.y;
      Bs[(k4 + 2) & 15][r] = wv.z; Bs[(k4 + 3) & 15][r] = wv.w;
    }
    __syncthreads();
#pragma unroll
    for (int k = 0; k < 16; ++k) {
      float a[8], bb[8];
      *(float4*)&a[0] = *(const float4*)&As[k][ty * 8];
      *(float4*)&a[4] = *(const float4*)&As[k][ty * 8 + 4];
      *(float4*)&bb[0] = *(const float4*)&Bs[k][tx * 8];
      *(float4*)&bb[4] = *(const float4*)&Bs[k][tx * 8 + 4];
#pragma unroll
      for (int i = 0; i < 8; ++i)
#pragma unroll
        for (int j = 0; j < 8; ++j) acc[i][j] = fmaf(a[i], bb[j], acc[i][j]);
    }
    __syncthreads();
  }

#pragma unroll
  for (int i = 0; i < 8; ++i) {
    int m = bm + ty * 8 + i;
    float* crow = C + (size_t)m * ldc;
#pragma unroll
    for (int j4 = 0; j4 < 2; ++j4) {
      int n0 = bn + tx * 8 + j4 * 4;
      if (n0 < N) {  // N is always a multiple of 4
        float4 o;
        const float* pa = &acc[i][j4 * 4];
        if (EPI == 0) {
          o = make_float4(pa[0], pa[1], pa[2], pa[3]);
        } else {
          float4 bb4 = *(const float4*)(bias + n0);
          o.x = softplus_f(pa[0] + bb4.x);
          o.y = softplus_f(pa[1] + bb4.y);
          o.z = softplus_f(pa[2] + bb4.z);
          o.w = softplus_f(pa[3] + bb4.w);
        }
        *(float4*)(crow + n0) = o;
      }
    }
  }
}

// ---------------- causal depthwise conv K=4 + bias + silu ----------------
__global__ void conv_silu_kernel(const float* __restrict__ xz, const float* __restrict__ wc,
                                 const float* __restrict__ bc, float* __restrict__ u) {
  size_t idx = (size_t)blockIdx.x * 256 + threadIdx.x;   // (b*L + l)*512 + d
  int d = (int)(idx & (DI - 1));
  size_t bl = idx >> 9;
  int l = (int)(bl & (LSEQ - 1));
  const float* base = xz + bl * 1024 + d;                // u half of xz
  float4 wv = *(const float4*)(wc + d * 4);
  float acc = bc[d] + wv.w * base[0];
  if (l >= 1) acc = fmaf(wv.z, base[-1024], acc);
  if (l >= 2) acc = fmaf(wv.y, base[-2048], acc);
  if (l >= 3) acc = fmaf(wv.x, base[-3072], acc);
  float s = acc / (1.f + __expf(-acc));
  u[bl * DI + d] = s;
}

// ================= chunked parallel selective scan =================
// pass 1: per-chunk decay P = exp(A * sum dt) and zero-state endpoint Q
__global__ __launch_bounds__(256, 8) void scan_pass1(
    const float* __restrict__ xz, const float* __restrict__ u,
    const float* __restrict__ xdbl, const float* __restrict__ A_log,
    float* __restrict__ P, float* __restrict__ Q) {
  int bx = blockIdx.x;
  int c = blockIdx.y;
  int b = bx >> 3, dblk = bx & 7;
  int tid = threadIdx.x;
  int lane = tid & 63, wave = tid >> 6;
  int dl = lane >> 2, sg = lane & 3;
  int d = dblk * 64 + wave * 16 + dl;
  float4 al = *(const float4*)(A_log + d * 16 + sg * 4);
  float A0 = -__expf(al.x), A1 = -__expf(al.y), A2 = -__expf(al.z), A3 = -__expf(al.w);
  float h0 = 0.f, h1 = 0.f, h2 = 0.f, h3 = 0.f, sumdt = 0.f;
  size_t mbase = (size_t)b * LSEQ + (size_t)c * CHUNK;
  for (int t = 0; t < CHUNK; ++t) {
    size_t m = mbase + t;
    float dtv = xz[m * 1024 + d];
    float uv = u[m * DI + d];
    float4 Bv = *(const float4*)(xdbl + m * 48 + 16 + sg * 4);
    sumdt += dtv;
    float dtu = dtv * uv;
    h0 = fmaf(__expf(dtv * A0), h0, dtu * Bv.x);
    h1 = fmaf(__expf(dtv * A1), h1, dtu * Bv.y);
    h2 = fmaf(__expf(dtv * A2), h2, dtu * Bv.z);
    h3 = fmaf(__expf(dtv * A3), h3, dtu * Bv.w);
  }
  size_t idx = ((size_t)(bx * NCHUNK + c) * 256 + tid) * 4;
  *(float4*)(Q + idx) = make_float4(h0, h1, h2, h3);
  *(float4*)(P + idx) = make_float4(__expf(A0 * sumdt), __expf(A1 * sumdt),
                                    __expf(A2 * sumdt), __expf(A3 * sumdt));
}

// combine: serial fold over the 32 chunks -> each chunk's initial state Hin
__global__ void scan_combine(const float* __restrict__ P, const float* __restrict__ Q,
                             float* __restrict__ Hin) {
  int bx = blockIdx.x;
  int tid = threadIdx.x;
  float4 h = make_float4(0.f, 0.f, 0.f, 0.f);
  for (int c = 0; c < NCHUNK; ++c) {
    size_t idx = ((size_t)(bx * NCHUNK + c) * 256 + tid) * 4;
    *(float4*)(Hin + idx) = h;
    float4 p = *(const float4*)(P + idx);
    float4 q = *(const float4*)(Q + idx);
    h.x = fmaf(p.x, h.x, q.x);
    h.y = fmaf(p.y, h.y, q.y);
    h.z = fmaf(p.z, h.z, q.z);
    h.w = fmaf(p.w, h.w, q.w);
  }
}

// pass 2: rerun recurrence from Hin, emit y + u*D, gate with silu(z), in-place over u
__global__ __launch_bounds__(256, 8) void scan_pass2(
    const float* __restrict__ xz, float* __restrict__ u,
    const float* __restrict__ xdbl, const float* __restrict__ A_log,
    const float* __restrict__ Dp, const float* __restrict__ Hin) {
  int bx = blockIdx.x;
  int c = blockIdx.y;
  int b = bx >> 3, dblk = bx & 7;
  int tid = threadIdx.x;
  int lane = tid & 63, wave = tid >> 6;
  int dl = lane >> 2, sg = lane & 3;
  int d = dblk * 64 + wave * 16 + dl;
  float4 al = *(const float4*)(A_log + d * 16 + sg * 4);
  float A0 = -__expf(al.x), A1 = -__expf(al.y), A2 = -__expf(al.z), A3 = -__expf(al.w);
  float Dd = Dp[d];
  size_t idx = ((size_t)(bx * NCHUNK + c) * 256 + tid) * 4;
  float4 h = *(const float4*)(Hin + idx);
  float h0 = h.x, h1 = h.y, h2 = h.z, h3 = h.w;
  size_t mbase = (size_t)b * LSEQ + (size_t)c * CHUNK;
  for (int t = 0; t < CHUNK; ++t) {
    size_t m = mbase + t;
    float dtv = xz[m * 1024 + d];
    float zv  = xz[m * 1024 + 512 + d];
    float uv  = u[m * DI + d];
    float4 Bv = *(const float4*)(xdbl + m * 48 + 16 + sg * 4);
    float4 Cv = *(const float4*)(xdbl + m * 48 + 32 + sg * 4);
    float dtu = dtv * uv;
    h0 = fmaf(__expf(dtv * A0), h0, dtu * Bv.x);
    h1 = fmaf(__expf(dtv * A1), h1, dtu * Bv.y);
    h2 = fmaf(__expf(dtv * A2), h2, dtu * Bv.z);
    h3 = fmaf(__expf(dtv * A3), h3, dtu * Bv.w);
    float y = h0 * Cv.x + h1 * Cv.y + h2 * Cv.z + h3 * Cv.w;
    y += __shfl_xor(y, 1);
    y += __shfl_xor(y, 2);
    if (sg == 0) {
      float yf = y + uv * Dd;
      float sz = zv / (1.f + __expf(-zv));
      u[m * DI + d] = yf * sz;
    }
  }
}

// ---------------- final LN + scatter back to raster order ----------------
__global__ void lnf_scatter_kernel(const float* __restrict__ x, const float* __restrict__ w,
                                   const float* __restrict__ bwt, const int* __restrict__ co,
                                   float* __restrict__ out) {
  int row = blockIdx.x;          // b*4096 + l
  int b = row >> 12;
  int l = row & (LSEQ - 1);
  int lane = threadIdx.x;
  float4 v = ((const float4*)(x + (size_t)row * DM))[lane];
  float s = v.x + v.y + v.z + v.w;
  float s2 = v.x * v.x + v.y * v.y + v.z * v.z + v.w * v.w;
#pragma unroll
  for (int off = 32; off > 0; off >>= 1) {
    s += __shfl_xor(s, off);
    s2 += __shfl_xor(s2, off);
  }
  float mu = s * (1.0f / DM);
  float var = s2 * (1.0f / DM) - mu * mu;
  float rstd = rsqrtf(var + 1e-5f);
  float4 wv = ((const float4*)w)[lane];
  float4 bv = ((const float4*)bwt)[lane];
  float4 o;
  o.x = (v.x - mu) * rstd * wv.x + bv.x;
  o.y = (v.y - mu) * rstd * wv.y + bv.y;
  o.z = (v.z - mu) * rstd * wv.z + bv.z;
  o.w = (v.w - mu) * rstd * wv.w + bv.w;
  int hw = co[l];
  int c0 = lane * 4;
  size_t obase = ((size_t)b * DM + c0) * 4096 + hw;
  out[obase + 0 * 4096] = o.x;
  out[obase + 1 * 4096] = o.y;
  out[obase + 2 * 4096] = o.z;
  out[obase + 3 * 4096] = o.w;
}

extern "C" void kernel_launch(void* const* d_in, const int* in_sizes, int n_in,
                              void* d_out, int out_size, void* d_ws, size_t ws_size,
                              hipStream_t stream) {
  (void)in_sizes; (void)n_in; (void)out_size; (void)ws_size;
  const float* sf   = (const float*)d_in[0];
  const float* lnw  = (const float*)d_in[1];
  const float* lnb  = (const float*)d_in[2];
  const float* inw  = (const float*)d_in[3];
  const float* cw   = (const float*)d_in[4];
  const float* cb   = (const float*)d_in[5];
  const float* xpw  = (const float*)d_in[6];
  const float* dtw  = (const float*)d_in[7];
  const float* dtb  = (const float*)d_in[8];
  const float* alog = (const float*)d_in[9];
  const float* dp   = (const float*)d_in[10];
  const float* ow   = (const float*)d_in[11];
  const float* lnfw = (const float*)d_in[12];
  const float* lnfb = (const float*)d_in[13];
  const int*   co   = (const int*)d_in[14];
  float* out = (float*)d_out;

  float* ws = (float*)d_ws;
  // workspace layout (floats): x 8.39M | x_ln(head)/x_dbl + P/Q/Hin 8.39M | xz 33.55M | u 16.78M
  float* x    = ws;
  float* xln  = ws + 8388608;
  float* xdbl = xln;                    // aliases x_ln (x_ln dead once x_proj runs)
  // x_dbl uses 32768*48 = 1572864 floats; scan scratch lives in the region's tail:
  float* P    = xln + 1572864;          // 2097152 floats
  float* Q    = P + 2097152;
  float* Hin  = Q + 2097152;            // ends at xln + 7864320 < 8388608
  float* xz   = ws + 16777216;
  float* u    = ws + 50331648;

  const int ROWS = NB * LSEQ;           // 32768

  gather_kernel<<<ROWS, 256, 0, stream>>>(sf, co, x);

  for (int i = 0; i < 4; ++i) {
    ln_kernel<<<ROWS, 64, 0, stream>>>(x, lnw + i * DM, lnb + i * DM, xln);
    // in_proj (bf16 MFMA): [32768,256] x [1024,256]^T -> xz [32768,1024]
    mfma_gemm<0><<<dim3(ROWS / 64, 1024 / 64), 256, 0, stream>>>(
        xln, DM, inw + (size_t)i * 1024 * DM, xz, 1024, DM);
    // causal depthwise conv + silu -> u
    conv_silu_kernel<<<(ROWS * DI) / 256, 256, 0, stream>>>(
        xz, cw + i * DI * 4, cb + i * DI, u);
    // x_proj (fp32): [32768,512] x [48,512]^T -> x_dbl [32768,48]
    gemm_kernel<0><<<dim3(ROWS / 128, 1), 256, 0, stream>>>(
        u, DI, xpw + (size_t)i * 48 * DI, xdbl, 48, 48, DI, nullptr);
    // dt_proj (fp32): [32768,16] x [512,16]^T + b, softplus -> dt stored in xz[:, :512]
    gemm_kernel<1><<<dim3(ROWS / 128, 4), 256, 0, stream>>>(
        xdbl, 48, dtw + (size_t)i * DI * 16, xz, 1024, DI, 16, dtb + i * DI);
    // chunked parallel selective scan
    scan_pass1<<<dim3(64, NCHUNK), 256, 0, stream>>>(
        xz, u, xdbl, alog + i * DI * 16, P, Q);
    scan_combine<<<64, 256, 0, stream>>>(P, Q, Hin);
    scan_pass2<<<dim3(64, NCHUNK), 256, 0, stream>>>(
        xz, u, xdbl, alog + i * DI * 16, dp + i * DI, Hin);
    // out_proj + residual (bf16 MFMA): x += y x [256,512]^T
    mfma_gemm<2><<<dim3(ROWS / 64, DM / 64), 256, 0, stream>>>(
        u, DI, ow + (size_t)i * DM * DI, x, DM, DI);
  }

  lnf_scatter_kernel<<<ROWS, 64, 0, stream>>>(x, lnfw, lnfb, co, out);
}